// Round 1
// baseline (29346.719 us; speedup 1.0000x reference)
//
#include <hip/hip_runtime.h>
#include <hip/hip_bf16.h>

#define BATCH 1024
#define HDIM 256
#define MLEN 80
#define LPRE 60
#define LFWD 80
#define KIN 32
#define KOUT 16

typedef unsigned short bf16_t;

__device__ __forceinline__ float bf2f(bf16_t v) {
    unsigned int u = ((unsigned int)v) << 16;
    return __uint_as_float(u);
}
__device__ __forceinline__ bf16_t f2bf(float f) {
    unsigned int u = __float_as_uint(f);
    unsigned int r = (u + 0x7FFFu + ((u >> 16) & 1u)) >> 16;
    return (bf16_t)r;
}
__device__ __forceinline__ float dot4(float4 a, float4 b) {
    return a.x * b.x + a.y * b.y + a.z * b.z + a.w * b.w;
}
__device__ __forceinline__ float sigm(float x) {
    return 1.0f / (1.0f + __expf(-x));
}

// ---------------------------------------------------------------------------
// Encoder step: emb = [x,y]@embW^T + embB ; gi = emb@Wih^T ; gh = h@Whh^T ;
// GRU elementwise -> h_next, enc_out[t] (bf16).
// Grid (64, 4): bx = batch tile of 16, by = 64-wide j-column chunk.
// ---------------------------------------------------------------------------
__global__ __launch_bounds__(256) void enc_step(
    const float* __restrict__ px, const float* __restrict__ py,
    const float* __restrict__ embW, const float* __restrict__ embB,
    const float* __restrict__ Wih, const float* __restrict__ Whh,
    const float* __restrict__ bih, const float* __restrict__ bhh,
    const float* __restrict__ hprev, float* __restrict__ hnext,
    bf16_t* __restrict__ enc_out_t)
{
    __shared__ float xy[16][48];
    __shared__ float es[16][260];
    __shared__ float hs[16][260];
    int tid = threadIdx.x;
    int bx = blockIdx.x, by = blockIdx.y;
    int b0 = bx * 16;

    for (int i = tid; i < 16 * 48; i += 256) {
        int r = i / 48, k = i - r * 48;
        xy[r][k] = (k < KIN) ? px[(b0 + r) * KIN + k]
                             : py[(b0 + r) * KOUT + (k - KIN)];
    }
    for (int i = tid; i < 16 * HDIM; i += 256) {
        int r = i >> 8, c = i & 255;
        hs[r][c] = hprev[(b0 + r) * HDIM + c];
    }
    __syncthreads();
    for (int i = tid; i < 16 * HDIM; i += 256) {
        int r = i >> 8, c = i & 255;
        float acc = embB[c];
        const float* w = embW + c * 48;
        #pragma unroll
        for (int k = 0; k < 48; k++) acc += xy[r][k] * w[k];
        es[r][c] = acc;
    }
    __syncthreads();

    int jj = tid & 63, rg = tid >> 6;
    int j = by * 64 + jj;
    const float* wir = Wih + (size_t)j * HDIM;
    const float* wiz = Wih + (size_t)(j + HDIM) * HDIM;
    const float* win = Wih + (size_t)(j + 2 * HDIM) * HDIM;
    const float* whr = Whh + (size_t)j * HDIM;
    const float* whz = Whh + (size_t)(j + HDIM) * HDIM;
    const float* whn = Whh + (size_t)(j + 2 * HDIM) * HDIM;

    float air[4] = {0,0,0,0}, aiz[4] = {0,0,0,0}, ain[4] = {0,0,0,0};
    float ahr[4] = {0,0,0,0}, ahz[4] = {0,0,0,0}, ahn[4] = {0,0,0,0};

    for (int k = 0; k < HDIM; k += 4) {
        float4 vir = *(const float4*)(wir + k);
        float4 viz = *(const float4*)(wiz + k);
        float4 vin = *(const float4*)(win + k);
        float4 vhr = *(const float4*)(whr + k);
        float4 vhz = *(const float4*)(whz + k);
        float4 vhn = *(const float4*)(whn + k);
        #pragma unroll
        for (int rr = 0; rr < 4; rr++) {
            int r = rg * 4 + rr;
            float4 e4 = *(const float4*)&es[r][k];
            float4 h4 = *(const float4*)&hs[r][k];
            air[rr] += dot4(e4, vir);
            aiz[rr] += dot4(e4, viz);
            ain[rr] += dot4(e4, vin);
            ahr[rr] += dot4(h4, vhr);
            ahz[rr] += dot4(h4, vhz);
            ahn[rr] += dot4(h4, vhn);
        }
    }
    float b_ir = bih[j], b_iz = bih[j + HDIM], b_in = bih[j + 2 * HDIM];
    float b_hr = bhh[j], b_hz = bhh[j + HDIM], b_hn = bhh[j + 2 * HDIM];
    #pragma unroll
    for (int rr = 0; rr < 4; rr++) {
        int r = rg * 4 + rr;
        float rv = sigm(air[rr] + b_ir + ahr[rr] + b_hr);
        float zv = sigm(aiz[rr] + b_iz + ahz[rr] + b_hz);
        float nv = tanhf(ain[rr] + b_in + rv * (ahn[rr] + b_hn));
        float hv = hs[r][j];
        float h2 = (1.0f - zv) * nv + zv * hv;
        hnext[(b0 + r) * HDIM + j] = h2;
        enc_out_t[(b0 + r) * HDIM + j] = f2bf(h2);
    }
}

// ---------------------------------------------------------------------------
// Decoder attention kernel: y_{t-1} = h@outW^T+outB (written to d_out[t-1]),
// e = [y,fx]@dembW^T + dembB, logits = [e,h]@attW^T + attB, softmax,
// ctx = sum_m aw[m] * enc_out[m,b,:].
// Grid (64, 8): bx = batch tile 16, by = 32-wide ctx col chunk.
// ---------------------------------------------------------------------------
__global__ __launch_bounds__(256) void dec_attn(
    const float* __restrict__ fx, const float* __restrict__ hprev,
    const float* __restrict__ outW, const float* __restrict__ outB,
    const float* __restrict__ dembW, const float* __restrict__ dembB,
    const float* __restrict__ attW, const float* __restrict__ attB,
    const bf16_t* __restrict__ enc_out,
    float* __restrict__ e_buf, float* __restrict__ ctx_buf,
    float* __restrict__ yout, int write_y)
{
    __shared__ float hs[16][260];
    __shared__ float es[16][260];
    __shared__ float yx[16][48];
    __shared__ float aw[16][80];
    __shared__ float red[16][17];
    __shared__ float rmax[16];
    __shared__ float rsum[16];
    int tid = threadIdx.x;
    int bx = blockIdx.x, by = blockIdx.y;
    int b0 = bx * 16;

    for (int i = tid; i < 16 * HDIM; i += 256) {
        int r = i >> 8, c = i & 255;
        hs[r][c] = hprev[(b0 + r) * HDIM + c];
    }
    __syncthreads();

    {   // y part of di (cols 0..16)
        int r = tid >> 4, o = tid & 15;
        float acc = 0.0f;
        if (write_y) {
            acc = outB[o];
            const float* w = outW + o * HDIM;
            for (int k = 0; k < HDIM; k += 4) {
                float4 w4 = *(const float4*)(w + k);
                float4 h4 = *(const float4*)&hs[r][k];
                acc += dot4(h4, w4);
            }
            if (by == 0) yout[(b0 + r) * KOUT + o] = acc;
        }
        yx[r][o] = acc;
    }
    for (int i = tid; i < 16 * KIN; i += 256) {   // fx part (cols 16..48)
        int r = i >> 5, k = i & 31;
        yx[r][KOUT + k] = fx[(b0 + r) * KIN + k];
    }
    __syncthreads();

    for (int i = tid; i < 16 * HDIM; i += 256) {   // e
        int r = i >> 8, c = i & 255;
        float acc = dembB[c];
        const float* w = dembW + c * 48;
        #pragma unroll
        for (int k = 0; k < 48; k++) acc += yx[r][k] * w[k];
        es[r][c] = acc;
        if (by == 0) e_buf[(b0 + r) * HDIM + c] = acc;
    }
    __syncthreads();

    for (int i = tid; i < 16 * MLEN; i += 256) {   // logits
        int r = i / MLEN, m = i - r * MLEN;
        float acc = attB[m];
        const float* w1 = attW + m * (2 * HDIM);
        const float* w2 = w1 + HDIM;
        for (int k = 0; k < HDIM; k += 4) {
            float4 a4 = *(const float4*)(w1 + k);
            float4 b4 = *(const float4*)(w2 + k);
            float4 e4 = *(const float4*)&es[r][k];
            float4 h4 = *(const float4*)&hs[r][k];
            acc += dot4(e4, a4) + dot4(h4, b4);
        }
        aw[r][m] = acc;
    }
    __syncthreads();

    {   // softmax: row max
        int r = tid >> 4, l = tid & 15;
        float vmax = -1e30f;
        for (int m = l; m < MLEN; m += 16) vmax = fmaxf(vmax, aw[r][m]);
        red[r][l] = vmax;
    }
    __syncthreads();
    if ((tid & 15) == 0) {
        int r = tid >> 4;
        float vmax = red[r][0];
        #pragma unroll
        for (int l = 1; l < 16; l++) vmax = fmaxf(vmax, red[r][l]);
        rmax[r] = vmax;
    }
    __syncthreads();
    {   // exp + partial sums
        int r = tid >> 4, l = tid & 15;
        float vm = rmax[r];
        float ps = 0.0f;
        for (int m = l; m < MLEN; m += 16) {
            float v = __expf(aw[r][m] - vm);
            aw[r][m] = v;
            ps += v;
        }
        red[r][l] = ps;
    }
    __syncthreads();
    if ((tid & 15) == 0) {
        int r = tid >> 4;
        float s = 0.0f;
        #pragma unroll
        for (int l = 0; l < 16; l++) s += red[r][l];
        rsum[r] = s;
    }
    __syncthreads();

    {   // ctx: cols [by*32, by*32+32), rows split 8x2; only m < LPRE (rest zero)
        int cl = tid & 31, rr = tid >> 5;
        int c = by * 32 + cl;
        #pragma unroll
        for (int rstep = 0; rstep < 2; rstep++) {
            int r = rr + rstep * 8;
            float inv = 1.0f / rsum[r];
            float acc = 0.0f;
            const bf16_t* ep = enc_out + (size_t)(b0 + r) * HDIM + c;
            for (int m = 0; m < LPRE; m++) {
                acc += aw[r][m] * bf2f(ep[(size_t)m * BATCH * HDIM]);
            }
            ctx_buf[(b0 + r) * HDIM + c] = acc * inv;
        }
    }
}

// ---------------------------------------------------------------------------
// g = tanh([e,ctx]@combW^T + combB). Grid (64,4).
// ---------------------------------------------------------------------------
__global__ __launch_bounds__(256) void dec_comb(
    const float* __restrict__ e_buf, const float* __restrict__ ctx_buf,
    const float* __restrict__ combW, const float* __restrict__ combB,
    float* __restrict__ g_buf)
{
    __shared__ float es[16][260];
    __shared__ float cs[16][260];
    int tid = threadIdx.x;
    int bx = blockIdx.x, by = blockIdx.y;
    int b0 = bx * 16;
    for (int i = tid; i < 16 * HDIM; i += 256) {
        int r = i >> 8, c = i & 255;
        es[r][c] = e_buf[(b0 + r) * HDIM + c];
        cs[r][c] = ctx_buf[(b0 + r) * HDIM + c];
    }
    __syncthreads();
    int jj = tid & 63, rg = tid >> 6;
    int c = by * 64 + jj;
    const float* w1 = combW + (size_t)c * (2 * HDIM);
    const float* w2 = w1 + HDIM;
    float acc[4] = {0,0,0,0};
    for (int k = 0; k < HDIM; k += 4) {
        float4 a4 = *(const float4*)(w1 + k);
        float4 b4 = *(const float4*)(w2 + k);
        #pragma unroll
        for (int rr = 0; rr < 4; rr++) {
            int r = rg * 4 + rr;
            float4 e4 = *(const float4*)&es[r][k];
            float4 c4 = *(const float4*)&cs[r][k];
            acc[rr] += dot4(e4, a4) + dot4(c4, b4);
        }
    }
    float bb = combB[c];
    #pragma unroll
    for (int rr = 0; rr < 4; rr++) {
        g_buf[(b0 + rg * 4 + rr) * HDIM + c] = tanhf(acc[rr] + bb);
    }
}

// ---------------------------------------------------------------------------
// Decoder GRU: gi = g@Wih^T, gh = h@Whh^T, elementwise -> h_next. Grid (64,4).
// ---------------------------------------------------------------------------
__global__ __launch_bounds__(256) void dec_gru(
    const float* __restrict__ g_buf,
    const float* __restrict__ Wih, const float* __restrict__ Whh,
    const float* __restrict__ bih, const float* __restrict__ bhh,
    const float* __restrict__ hprev, float* __restrict__ hnext)
{
    __shared__ float gs[16][260];
    __shared__ float hs[16][260];
    int tid = threadIdx.x;
    int bx = blockIdx.x, by = blockIdx.y;
    int b0 = bx * 16;
    for (int i = tid; i < 16 * HDIM; i += 256) {
        int r = i >> 8, c = i & 255;
        gs[r][c] = g_buf[(b0 + r) * HDIM + c];
        hs[r][c] = hprev[(b0 + r) * HDIM + c];
    }
    __syncthreads();

    int jj = tid & 63, rg = tid >> 6;
    int j = by * 64 + jj;
    const float* wir = Wih + (size_t)j * HDIM;
    const float* wiz = Wih + (size_t)(j + HDIM) * HDIM;
    const float* win = Wih + (size_t)(j + 2 * HDIM) * HDIM;
    const float* whr = Whh + (size_t)j * HDIM;
    const float* whz = Whh + (size_t)(j + HDIM) * HDIM;
    const float* whn = Whh + (size_t)(j + 2 * HDIM) * HDIM;

    float air[4] = {0,0,0,0}, aiz[4] = {0,0,0,0}, ain[4] = {0,0,0,0};
    float ahr[4] = {0,0,0,0}, ahz[4] = {0,0,0,0}, ahn[4] = {0,0,0,0};

    for (int k = 0; k < HDIM; k += 4) {
        float4 vir = *(const float4*)(wir + k);
        float4 viz = *(const float4*)(wiz + k);
        float4 vin = *(const float4*)(win + k);
        float4 vhr = *(const float4*)(whr + k);
        float4 vhz = *(const float4*)(whz + k);
        float4 vhn = *(const float4*)(whn + k);
        #pragma unroll
        for (int rr = 0; rr < 4; rr++) {
            int r = rg * 4 + rr;
            float4 g4 = *(const float4*)&gs[r][k];
            float4 h4 = *(const float4*)&hs[r][k];
            air[rr] += dot4(g4, vir);
            aiz[rr] += dot4(g4, viz);
            ain[rr] += dot4(g4, vin);
            ahr[rr] += dot4(h4, vhr);
            ahz[rr] += dot4(h4, vhz);
            ahn[rr] += dot4(h4, vhn);
        }
    }
    float b_ir = bih[j], b_iz = bih[j + HDIM], b_in = bih[j + 2 * HDIM];
    float b_hr = bhh[j], b_hz = bhh[j + HDIM], b_hn = bhh[j + 2 * HDIM];
    #pragma unroll
    for (int rr = 0; rr < 4; rr++) {
        int r = rg * 4 + rr;
        float rv = sigm(air[rr] + b_ir + ahr[rr] + b_hr);
        float zv = sigm(aiz[rr] + b_iz + ahz[rr] + b_hz);
        float nv = tanhf(ain[rr] + b_in + rv * (ahn[rr] + b_hn));
        float hv = hs[r][j];
        float h2 = (1.0f - zv) * nv + zv * hv;
        hnext[(b0 + r) * HDIM + j] = h2;
    }
}

// ---------------------------------------------------------------------------
// Final y_79 = h@outW^T + outB. Grid (64).
// ---------------------------------------------------------------------------
__global__ __launch_bounds__(256) void final_out(
    const float* __restrict__ hfin, const float* __restrict__ outW,
    const float* __restrict__ outB, float* __restrict__ yout)
{
    __shared__ float hs[16][260];
    int tid = threadIdx.x, bx = blockIdx.x;
    int b0 = bx * 16;
    for (int i = tid; i < 16 * HDIM; i += 256) {
        int r = i >> 8, c = i & 255;
        hs[r][c] = hfin[(b0 + r) * HDIM + c];
    }
    __syncthreads();
    int r = tid >> 4, o = tid & 15;
    float acc = outB[o];
    const float* w = outW + o * HDIM;
    for (int k = 0; k < HDIM; k += 4) {
        float4 w4 = *(const float4*)(w + k);
        float4 h4 = *(const float4*)&hs[r][k];
        acc += dot4(h4, w4);
    }
    yout[(b0 + r) * KOUT + o] = acc;
}

extern "C" void kernel_launch(void* const* d_in, const int* in_sizes, int n_in,
                              void* d_out, int out_size, void* d_ws, size_t ws_size,
                              hipStream_t stream) {
    const float* pre_x    = (const float*)d_in[0];
    const float* pre_y    = (const float*)d_in[1];
    const float* fwd_x    = (const float*)d_in[2];
    const float* enc_embW = (const float*)d_in[3];
    const float* enc_embB = (const float*)d_in[4];
    const float* enc_Wih  = (const float*)d_in[5];
    const float* enc_Whh  = (const float*)d_in[6];
    const float* enc_bih  = (const float*)d_in[7];
    const float* enc_bhh  = (const float*)d_in[8];
    const float* dec_embW = (const float*)d_in[9];
    const float* dec_embB = (const float*)d_in[10];
    const float* attn_W   = (const float*)d_in[11];
    const float* attn_b   = (const float*)d_in[12];
    const float* comb_W   = (const float*)d_in[13];
    const float* comb_b   = (const float*)d_in[14];
    const float* dec_Wih  = (const float*)d_in[15];
    const float* dec_Whh  = (const float*)d_in[16];
    const float* dec_bih  = (const float*)d_in[17];
    const float* dec_bhh  = (const float*)d_in[18];
    const float* out_W    = (const float*)d_in[19];
    const float* out_b    = (const float*)d_in[20];
    float* out = (float*)d_out;

    char* ws = (char*)d_ws;
    bf16_t* enc_out = (bf16_t*)ws;                       // [80,1024,256] bf16
    size_t off = (size_t)MLEN * BATCH * HDIM * 2;
    float* h0      = (float*)(ws + off); off += (size_t)BATCH * HDIM * 4;
    float* h1      = (float*)(ws + off); off += (size_t)BATCH * HDIM * 4;
    float* e_buf   = (float*)(ws + off); off += (size_t)BATCH * HDIM * 4;
    float* ctx_buf = (float*)(ws + off); off += (size_t)BATCH * HDIM * 4;
    float* g_buf   = (float*)(ws + off); off += (size_t)BATCH * HDIM * 4;

    // zero the t >= LPRE padding of enc_out (softmax uses those slots but
    // ctx skips them; still zero for safety) and the initial hidden state
    hipMemsetAsync(enc_out + (size_t)LPRE * BATCH * HDIM, 0,
                   (size_t)(MLEN - LPRE) * BATCH * HDIM * 2, stream);
    hipMemsetAsync(h0, 0, (size_t)BATCH * HDIM * 4, stream);

    float* hb[2] = {h0, h1};
    dim3 blk(256);

    for (int t = 0; t < LPRE; t++) {
        enc_step<<<dim3(BATCH / 16, 4), blk, 0, stream>>>(
            pre_x + (size_t)t * BATCH * KIN, pre_y + (size_t)t * BATCH * KOUT,
            enc_embW, enc_embB, enc_Wih, enc_Whh, enc_bih, enc_bhh,
            hb[t & 1], hb[(t + 1) & 1], enc_out + (size_t)t * BATCH * HDIM);
    }
    for (int t = 0; t < LFWD; t++) {
        dec_attn<<<dim3(BATCH / 16, 8), blk, 0, stream>>>(
            fwd_x + (size_t)t * BATCH * KIN, hb[t & 1],
            out_W, out_b, dec_embW, dec_embB, attn_W, attn_b,
            enc_out, e_buf, ctx_buf,
            (t > 0) ? (out + (size_t)(t - 1) * BATCH * KOUT) : out,
            (t > 0) ? 1 : 0);
        dec_comb<<<dim3(BATCH / 16, 4), blk, 0, stream>>>(
            e_buf, ctx_buf, comb_W, comb_b, g_buf);
        dec_gru<<<dim3(BATCH / 16, 4), blk, 0, stream>>>(
            g_buf, dec_Wih, dec_Whh, dec_bih, dec_bhh,
            hb[t & 1], hb[(t + 1) & 1]);
    }
    final_out<<<dim3(BATCH / 16), blk, 0, stream>>>(
        hb[LFWD & 1], out_W, out_b, out + (size_t)(LFWD - 1) * BATCH * KOUT);
}

// Round 2
// 2989.659 us; speedup vs baseline: 9.8161x; 9.8161x over previous
//
#include <hip/hip_runtime.h>
#include <hip/hip_bf16.h>

#define BATCH 1024
#define HD 256
#define MLEN 80
#define LPRE 60
#define LFWD 80
#define KIN 32
#define KOUT 16

typedef unsigned short bf16_t;
typedef __attribute__((ext_vector_type(8))) short bf16x8;
typedef __attribute__((ext_vector_type(4))) float f32x4;

__device__ __forceinline__ float bf2f(bf16_t v){ return __uint_as_float(((unsigned)v)<<16); }
__device__ __forceinline__ bf16_t f2bf(float f){
    unsigned u = __float_as_uint(f);
    return (bf16_t)((u + 0x7FFFu + ((u>>16)&1u)) >> 16);
}
__device__ __forceinline__ unsigned pack2(float lo, float hi){
    return (unsigned)f2bf(lo) | ((unsigned)f2bf(hi)<<16);
}
__device__ __forceinline__ float sigm(float x){ return 1.0f/(1.0f+__expf(-x)); }

// Packed-B byte offsets inside a GRU weight pack (4 N-groups):
// r:[0,262144) z:[262144,524288) in:[524288,655360) hn:[655360,786432)
#define OFF_Z  262144
#define OFF_IN 524288
#define OFF_HN 655360

// ---------------------------------------------------------------------------
// Pack GRU weights: B[k][n] fragment-tiled bf16. grid 192x256 (one 16B chunk/thread)
// ---------------------------------------------------------------------------
__global__ void pack_gru(const float* __restrict__ Wih, const float* __restrict__ Whh,
                         bf16_t* __restrict__ dst)
{
    int T = blockIdx.x*256 + threadIdx.x;   // < 49152
    int grp, local;
    if (T < 16384){ grp=0; local=T; }
    else if (T < 32768){ grp=1; local=T-16384; }
    else if (T < 40960){ grp=2; local=T-32768; }
    else { grp=3; local=T-40960; }
    int nkt = (grp<2)?16:8;
    int nt  = local / (nkt*64);
    int rem = local - nt*(nkt*64);
    int kt  = rem >> 6;
    int l   = rem & 63;
    int n   = nt*16 + (l&15);
    int k0  = kt*32 + ((l>>4)<<3);
    unsigned w[4];
    #pragma unroll
    for (int h2=0; h2<4; h2++){
        float v[2];
        #pragma unroll
        for (int s=0; s<2; s++){
            int k = k0 + h2*2 + s;
            if (grp==0)      v[s] = (k<256)? Wih[(size_t)n*HD + k]       : Whh[(size_t)n*HD + (k-256)];
            else if (grp==1) v[s] = (k<256)? Wih[(size_t)(256+n)*HD + k] : Whh[(size_t)(256+n)*HD + (k-256)];
            else if (grp==2) v[s] = Wih[(size_t)(512+n)*HD + k];
            else             v[s] = Whh[(size_t)(512+n)*HD + k];
        }
        w[h2] = pack2(v[0], v[1]);
    }
    uint4 u = {w[0],w[1],w[2],w[3]};
    *(uint4*)((char*)dst + (size_t)T*16) = u;
}

// ---------------------------------------------------------------------------
// Pack K=512,N=256 B from W[256][512] (combW): B[k][n]=W[n][k]. grid 64x256
// ---------------------------------------------------------------------------
__global__ void pack_B512(const float* __restrict__ W, bf16_t* __restrict__ dst)
{
    int T = blockIdx.x*256 + threadIdx.x;   // < 16384
    int nt = T >> 10, kt = (T>>6)&15, l = T&63;
    int n = nt*16 + (l&15);
    int k0 = kt*32 + ((l>>4)<<3);
    unsigned w[4];
    #pragma unroll
    for (int h2=0; h2<4; h2++)
        w[h2] = pack2(W[(size_t)n*512 + k0+h2*2], W[(size_t)n*512 + k0+h2*2+1]);
    uint4 u = {w[0],w[1],w[2],w[3]};
    *(uint4*)((char*)dst + (size_t)T*16) = u;
}

// ---------------------------------------------------------------------------
// Wfuse[k][n] = sum_o dembW[n][o]*outW[o][k]; e_bias[n]=dembB[n]+sum_o outB[o]*dembW[n][o]
// grid 257x256
// ---------------------------------------------------------------------------
__global__ void wfuse_kernel(const float* __restrict__ dembW, const float* __restrict__ dembB,
                             const float* __restrict__ outW, const float* __restrict__ outB,
                             float* __restrict__ Wfuse, float* __restrict__ ebias)
{
    int T = blockIdx.x*256 + threadIdx.x;
    if (T < 65536){
        int k = T >> 8, n = T & 255;
        float acc = 0.f;
        #pragma unroll
        for (int o=0;o<16;o++) acc += dembW[(size_t)n*48 + o]*outW[(size_t)o*HD + k];
        Wfuse[(size_t)k*HD + n] = acc;
    } else if (T < 65792){
        int n = T - 65536;
        float acc = dembB[n];
        #pragma unroll
        for (int o=0;o<16;o++) acc += outB[o]*dembW[(size_t)n*48 + o];
        ebias[n] = acc;
    }
}

// ---------------------------------------------------------------------------
// Pack B_e [K=288][N=256]: kt<8 -> Wfuse[k][n]; kt==8 -> dembW[n][16+k']. grid 36x256
// ---------------------------------------------------------------------------
__global__ void pack_e(const float* __restrict__ Wfuse, const float* __restrict__ dembW,
                       bf16_t* __restrict__ dst)
{
    int T = blockIdx.x*256 + threadIdx.x;   // < 9216
    int nt = T/576, rem = T - nt*576;
    int kt = rem >> 6, l = rem & 63;
    int n = nt*16 + (l&15);
    int k0 = kt*32 + ((l>>4)<<3);
    unsigned w[4];
    #pragma unroll
    for (int h2=0; h2<4; h2++){
        float v[2];
        #pragma unroll
        for (int s=0;s<2;s++){
            int k = k0 + h2*2 + s;
            v[s] = (kt<8)? Wfuse[(size_t)k*HD + n] : dembW[(size_t)n*48 + 16 + (k-256)];
        }
        w[h2] = pack2(v[0], v[1]);
    }
    uint4 u = {w[0],w[1],w[2],w[3]};
    *(uint4*)((char*)dst + (size_t)T*16) = u;
}

// ---------------------------------------------------------------------------
// Pack logits B (t>=1 and t==0 variants) + bias vectors. grid 24x256
// B_L [K=288][N=80]: kt<8: sum_n Wfuse[k][n]attW[m][n] + attW[m][256+k]; kt==8: W_fxL
// B_L0: kt<8: attW[m][256+k]; kt==8: W_fxL.  lb/lb0: folded biases.
// ---------------------------------------------------------------------------
__global__ void pack_logits(const float* __restrict__ Wfuse, const float* __restrict__ dembW,
                            const float* __restrict__ attW, const float* __restrict__ attB,
                            const float* __restrict__ dembB, const float* __restrict__ ebias,
                            bf16_t* __restrict__ BL, bf16_t* __restrict__ BL0,
                            float* __restrict__ lb, float* __restrict__ lb0)
{
    int T = blockIdx.x*256 + threadIdx.x;
    if (T < 5760){
        int variant = (T < 2880) ? 0 : 1;
        int local = variant ? (T-2880) : T;
        int nt = local/576, rem = local - nt*576;
        int kt = rem >> 6, l = rem & 63;
        int m  = nt*16 + (l&15);
        int k0 = kt*32 + ((l>>4)<<3);
        unsigned w[4];
        #pragma unroll
        for (int h2=0; h2<4; h2++){
            float v[2];
            for (int s=0;s<2;s++){
                int k = k0 + h2*2 + s;
                float acc;
                if (kt < 8){
                    if (variant == 0){
                        acc = attW[(size_t)m*512 + 256 + k];
                        for (int n=0;n<256;n++) acc += Wfuse[(size_t)k*HD + n]*attW[(size_t)m*512 + n];
                    } else {
                        acc = attW[(size_t)m*512 + 256 + k];
                    }
                } else {
                    int kp = k - 256;
                    acc = 0.f;
                    for (int n=0;n<256;n++) acc += dembW[(size_t)n*48 + 16 + kp]*attW[(size_t)m*512 + n];
                }
                v[s] = acc;
            }
            w[h2] = pack2(v[0], v[1]);
        }
        uint4 u = {w[0],w[1],w[2],w[3]};
        bf16_t* d = variant ? BL0 : BL;
        *(uint4*)((char*)d + (size_t)local*16) = u;
    } else if (T < 5840){
        int m = T - 5760;
        float acc = attB[m];
        for (int n=0;n<256;n++) acc += ebias[n]*attW[(size_t)m*512 + n];
        lb[m] = acc;
    } else if (T < 5920){
        int m = T - 5840;
        float acc = attB[m];
        for (int n=0;n<256;n++) acc += dembB[n]*attW[(size_t)m*512 + n];
        lb0[m] = acc;
    }
}

// ---------------------------------------------------------------------------
// All 60 encoder embeddings -> bf16. grid (64,60)x256
// ---------------------------------------------------------------------------
__global__ __launch_bounds__(256) void emb_kernel(
    const float* __restrict__ px, const float* __restrict__ py,
    const float* __restrict__ embW, const float* __restrict__ embB,
    bf16_t* __restrict__ emb)
{
    __shared__ float Ws[256*49];
    __shared__ float xy[16][48];
    __shared__ float bs[256];
    int t = blockIdx.y, b0 = blockIdx.x*16, tid = threadIdx.x;
    for (int i = tid; i < 256*48; i += 256){ int n=i/48, k=i-n*48; Ws[n*49+k]=embW[i]; }
    bs[tid] = embB[tid];
    for (int i = tid; i < 16*48; i += 256){
        int r=i/48, k=i-r*48;
        xy[r][k] = (k<KIN)? px[((size_t)t*BATCH + b0+r)*KIN + k]
                          : py[((size_t)t*BATCH + b0+r)*KOUT + (k-KIN)];
    }
    __syncthreads();
    int n = tid;
    const float* w = &Ws[n*49];
    for (int r=0;r<16;r++){
        float acc = bs[n];
        #pragma unroll
        for (int k=0;k<48;k++) acc += xy[r][k]*w[k];
        emb[((size_t)t*BATCH + b0+r)*HD + n] = f2bf(acc);
    }
}

// fx f32 -> bf16. grid 1280x256, one 8-elem chunk/thread
__global__ void fxconv(const float* __restrict__ fx, bf16_t* __restrict__ dst)
{
    size_t i = (size_t)blockIdx.x*256 + threadIdx.x;
    const float4* s = (const float4*)(fx + i*8);
    float4 a = s[0], b = s[1];
    uint4 u = { pack2(a.x,a.y), pack2(a.z,a.w), pack2(b.x,b.y), pack2(b.z,b.w) };
    *(uint4*)(dst + i*8) = u;
}

// ---------------------------------------------------------------------------
// Fused GRU step (enc & dec): C[1024,768] = [A0|A1]@B_cat, GRU epilogue.
// grid (64,4)x256. A0 = emb_t or g, A1 = h bf16. extra_bf = enc_out[t] or hist[t].
// ---------------------------------------------------------------------------
__global__ __launch_bounds__(256) void gru_step(
    const bf16_t* __restrict__ A0, const bf16_t* __restrict__ A1,
    const bf16_t* __restrict__ Bp,
    const float* __restrict__ bih, const float* __restrict__ bhh,
    const float* __restrict__ hprev, float* __restrict__ hnext,
    bf16_t* __restrict__ hnext_bf, bf16_t* __restrict__ extra_bf)
{
    __shared__ __align__(16) bf16_t As[16][520];
    int tid = threadIdx.x, b0 = blockIdx.x*16;
    for (int i = tid; i < 1024; i += 256){
        int r = i>>6, c = i&63;
        const bf16_t* src = (c<32)? (A0 + (size_t)(b0+r)*HD + c*8)
                                  : (A1 + (size_t)(b0+r)*HD + (c-32)*8);
        *(uint4*)&As[r][c*8] = *(const uint4*)src;
    }
    __syncthreads();
    int lane = tid & 63, wave = tid >> 6;
    int jt = blockIdx.y*4 + wave;
    const char* arow = (const char*)&As[lane&15][(lane>>4)*8];
    const char* bpc = (const char*)Bp;
    size_t loff = (size_t)lane*16;
    f32x4 cr={0,0,0,0}, cz={0,0,0,0}, ci={0,0,0,0}, ch={0,0,0,0};
    #pragma unroll
    for (int kt=0; kt<16; kt++){
        bf16x8 a  = *(const bf16x8*)(arow + kt*64);
        bf16x8 br = *(const bf16x8*)(bpc + (size_t)(((jt<<4)+kt)<<10) + loff);
        bf16x8 bz = *(const bf16x8*)(bpc + OFF_Z + (size_t)(((jt<<4)+kt)<<10) + loff);
        cr = __builtin_amdgcn_mfma_f32_16x16x32_bf16(a, br, cr, 0,0,0);
        cz = __builtin_amdgcn_mfma_f32_16x16x32_bf16(a, bz, cz, 0,0,0);
        if (kt < 8){
            bf16x8 bi = *(const bf16x8*)(bpc + OFF_IN + (size_t)(((jt<<3)+kt)<<10) + loff);
            ci = __builtin_amdgcn_mfma_f32_16x16x32_bf16(a, bi, ci, 0,0,0);
        } else {
            bf16x8 bh = *(const bf16x8*)(bpc + OFF_HN + (size_t)(((jt<<3)+kt-8)<<10) + loff);
            ch = __builtin_amdgcn_mfma_f32_16x16x32_bf16(a, bh, ch, 0,0,0);
        }
    }
    int j = (jt<<4) + (lane&15);
    float b_r = bih[j] + bhh[j];
    float b_z = bih[256+j] + bhh[256+j];
    float b_i = bih[512+j], b_h = bhh[512+j];
    #pragma unroll
    for (int q=0;q<4;q++){
        int b = b0 + ((lane>>4)<<2) + q;
        float rv = sigm(cr[q] + b_r);
        float zv = sigm(cz[q] + b_z);
        float nv = tanhf(ci[q] + b_i + rv*(ch[q] + b_h));
        float h2 = (1.0f - zv)*nv + zv*hprev[(size_t)b*HD + j];
        hnext[(size_t)b*HD + j] = h2;
        bf16_t hb = f2bf(h2);
        hnext_bf[(size_t)b*HD + j] = hb;
        extra_bf[(size_t)b*HD + j] = hb;
    }
}

// ---------------------------------------------------------------------------
// e = [h|fx_t]@B_e + ebias -> bf16. grid (64,4)x256. kt0=8 at t=0 (skip h part).
// ---------------------------------------------------------------------------
__global__ __launch_bounds__(256) void e_kernel(
    const bf16_t* __restrict__ hbf, const bf16_t* __restrict__ fxt,
    const bf16_t* __restrict__ Bp, const float* __restrict__ ebias,
    int kt0, bf16_t* __restrict__ e_out)
{
    __shared__ __align__(16) bf16_t As[16][296];
    int tid = threadIdx.x, b0 = blockIdx.x*16;
    for (int i = tid; i < 576; i += 256){
        int r = i/36, c = i - r*36;
        const bf16_t* src = (c<32)? (hbf + (size_t)(b0+r)*HD + c*8)
                                  : (fxt + (size_t)(b0+r)*KIN + (c-32)*8);
        *(uint4*)&As[r][c*8] = *(const uint4*)src;
    }
    __syncthreads();
    int lane = tid & 63, wave = tid >> 6;
    int nt = blockIdx.y*4 + wave;
    const char* arow = (const char*)&As[lane&15][(lane>>4)*8];
    const char* bpc = (const char*)Bp;
    size_t loff = (size_t)lane*16;
    f32x4 c = {0,0,0,0};
    for (int kt=kt0; kt<9; kt++){
        bf16x8 a = *(const bf16x8*)(arow + kt*64);
        bf16x8 b = *(const bf16x8*)(bpc + (size_t)((nt*9+kt)<<10) + loff);
        c = __builtin_amdgcn_mfma_f32_16x16x32_bf16(a, b, c, 0,0,0);
    }
    int n = (nt<<4) + (lane&15);
    float bb = ebias[n];
    #pragma unroll
    for (int q=0;q<4;q++){
        int b = b0 + ((lane>>4)<<2) + q;
        e_out[(size_t)b*HD + n] = f2bf(c[q] + bb);
    }
}

// ---------------------------------------------------------------------------
// logits = [h|fx]@B_L + lb -> softmax -> normalized aw. grid 64x256.
// ---------------------------------------------------------------------------
__global__ __launch_bounds__(256) void attn_kernel(
    const bf16_t* __restrict__ hbf, const bf16_t* __restrict__ fxt,
    const bf16_t* __restrict__ BL, const float* __restrict__ lb,
    float* __restrict__ aw)
{
    __shared__ __align__(16) bf16_t As[16][296];
    __shared__ float lg[16][84];
    __shared__ float red[16][17];
    __shared__ float rmax[16], rsum[16];
    int tid = threadIdx.x, b0 = blockIdx.x*16;
    for (int i = tid; i < 576; i += 256){
        int r = i/36, c = i - r*36;
        const bf16_t* src = (c<32)? (hbf + (size_t)(b0+r)*HD + c*8)
                                  : (fxt + (size_t)(b0+r)*KIN + (c-32)*8);
        *(uint4*)&As[r][c*8] = *(const uint4*)src;
    }
    __syncthreads();
    int lane = tid & 63, wave = tid >> 6;
    const char* arow = (const char*)&As[lane&15][(lane>>4)*8];
    const char* bpc = (const char*)BL;
    size_t loff = (size_t)lane*16;
    for (int nt = wave; nt < 5; nt += 4){
        f32x4 c = {0,0,0,0};
        #pragma unroll
        for (int kt=0; kt<9; kt++){
            bf16x8 a = *(const bf16x8*)(arow + kt*64);
            bf16x8 b = *(const bf16x8*)(bpc + (size_t)((nt*9+kt)<<10) + loff);
            c = __builtin_amdgcn_mfma_f32_16x16x32_bf16(a, b, c, 0,0,0);
        }
        int m = (nt<<4) + (lane&15);
        float bb = lb[m];
        #pragma unroll
        for (int q=0;q<4;q++) lg[((lane>>4)<<2)+q][m] = c[q] + bb;
    }
    __syncthreads();
    int r = tid>>4, l2 = tid&15;
    float vmax = -1e30f;
    for (int m=l2; m<80; m+=16) vmax = fmaxf(vmax, lg[r][m]);
    red[r][l2] = vmax; __syncthreads();
    if (l2==0){ float v=red[r][0]; for(int i=1;i<16;i++) v=fmaxf(v,red[r][i]); rmax[r]=v; }
    __syncthreads();
    float vm = rmax[r], ps = 0.f;
    for (int m=l2; m<80; m+=16){ float v=__expf(lg[r][m]-vm); lg[r][m]=v; ps+=v; }
    red[r][l2] = ps; __syncthreads();
    if (l2==0){ float s=0; for(int i=0;i<16;i++) s+=red[r][i]; rsum[r]=s; }
    __syncthreads();
    float inv = 1.0f/rsum[r];
    for (int m=l2; m<80; m+=16) aw[(size_t)(b0+r)*80 + m] = lg[r][m]*inv;
}

// ---------------------------------------------------------------------------
// ctx[b][c] = sum_{m<60} aw[b][m]*enc_out[m][b][c] -> bf16. grid (64,8)x256.
// ---------------------------------------------------------------------------
__global__ __launch_bounds__(256) void ctx_kernel(
    const float* __restrict__ aw, const bf16_t* __restrict__ enc_out,
    bf16_t* __restrict__ ctx)
{
    __shared__ float aws[16][61];
    int tid = threadIdx.x, b0 = blockIdx.x*16, c0 = blockIdx.y*32;
    for (int i = tid; i < 960; i += 256){
        int r = i/60, m = i - r*60;
        aws[r][m] = aw[(size_t)(b0+r)*80 + m];
    }
    __syncthreads();
    int c = tid&31, rr = tid>>5;
    #pragma unroll
    for (int half=0; half<2; half++){
        int r = rr + half*8;
        float acc = 0.f;
        const bf16_t* p = enc_out + (size_t)(b0+r)*HD + (c0+c);
        for (int m=0;m<60;m++) acc += aws[r][m]*bf2f(p[(size_t)m*BATCH*HD]);
        ctx[(size_t)(b0+r)*HD + c0+c] = f2bf(acc);
    }
}

// ---------------------------------------------------------------------------
// g = tanh([e|ctx]@B_comb + comb_b) -> bf16. grid (64,4)x256.
// ---------------------------------------------------------------------------
__global__ __launch_bounds__(256) void comb_kernel(
    const bf16_t* __restrict__ e, const bf16_t* __restrict__ ctx,
    const bf16_t* __restrict__ Bp, const float* __restrict__ cb,
    bf16_t* __restrict__ g)
{
    __shared__ __align__(16) bf16_t As[16][520];
    int tid = threadIdx.x, b0 = blockIdx.x*16;
    for (int i = tid; i < 1024; i += 256){
        int r = i>>6, c = i&63;
        const bf16_t* src = (c<32)? (e + (size_t)(b0+r)*HD + c*8)
                                  : (ctx + (size_t)(b0+r)*HD + (c-32)*8);
        *(uint4*)&As[r][c*8] = *(const uint4*)src;
    }
    __syncthreads();
    int lane = tid & 63, wave = tid >> 6;
    int nt = blockIdx.y*4 + wave;
    const char* arow = (const char*)&As[lane&15][(lane>>4)*8];
    const char* bpc = (const char*)Bp;
    size_t loff = (size_t)lane*16;
    f32x4 c = {0,0,0,0};
    #pragma unroll
    for (int kt=0; kt<16; kt++){
        bf16x8 a = *(const bf16x8*)(arow + kt*64);
        bf16x8 b = *(const bf16x8*)(bpc + (size_t)(((nt<<4)+kt)<<10) + loff);
        c = __builtin_amdgcn_mfma_f32_16x16x32_bf16(a, b, c, 0,0,0);
    }
    int n = (nt<<4) + (lane&15);
    float bb = cb[n];
    #pragma unroll
    for (int q=0;q<4;q++){
        int b = b0 + ((lane>>4)<<2) + q;
        g[(size_t)b*HD + n] = f2bf(tanhf(c[q] + bb));
    }
}

// ---------------------------------------------------------------------------
// ys[t] = h_hist[t]@outW^T + outB (f32 out). grid (64,80)x256.
// ---------------------------------------------------------------------------
__global__ __launch_bounds__(256) void final_out(
    const bf16_t* __restrict__ hist, const float* __restrict__ outW,
    const float* __restrict__ outB, float* __restrict__ ys)
{
    __shared__ float hs[16][256];
    __shared__ float ow[16*260];
    __shared__ float ob[16];
    int tid = threadIdx.x, b0 = blockIdx.x*16, t = blockIdx.y;
    for (int i = tid; i < 4096; i += 256){
        int o = i>>8, k = i&255;
        ow[o*260+k] = outW[(size_t)o*HD + k];
    }
    if (tid < 16) ob[tid] = outB[tid];
    for (int i = tid; i < 4096; i += 256){
        int r = i>>8, k = i&255;
        hs[r][k] = bf2f(hist[((size_t)t*BATCH + b0+r)*HD + k]);
    }
    __syncthreads();
    int r = tid>>4, o = tid&15;
    float acc = ob[o];
    const float* w = &ow[o*260];
    for (int k=0;k<256;k++) acc += hs[r][k]*w[k];
    ys[((size_t)t*BATCH + b0+r)*KOUT + o] = acc;
}

// ---------------------------------------------------------------------------
extern "C" void kernel_launch(void* const* d_in, const int* in_sizes, int n_in,
                              void* d_out, int out_size, void* d_ws, size_t ws_size,
                              hipStream_t stream) {
    const float* pre_x    = (const float*)d_in[0];
    const float* pre_y    = (const float*)d_in[1];
    const float* fwd_x    = (const float*)d_in[2];
    const float* enc_embW = (const float*)d_in[3];
    const float* enc_embB = (const float*)d_in[4];
    const float* enc_Wih  = (const float*)d_in[5];
    const float* enc_Whh  = (const float*)d_in[6];
    const float* enc_bih  = (const float*)d_in[7];
    const float* enc_bhh  = (const float*)d_in[8];
    const float* dec_embW = (const float*)d_in[9];
    const float* dec_embB = (const float*)d_in[10];
    const float* attn_W   = (const float*)d_in[11];
    const float* attn_b   = (const float*)d_in[12];
    const float* comb_W   = (const float*)d_in[13];
    const float* comb_b   = (const float*)d_in[14];
    const float* dec_Wih  = (const float*)d_in[15];
    const float* dec_Whh  = (const float*)d_in[16];
    const float* dec_bih  = (const float*)d_in[17];
    const float* dec_bhh  = (const float*)d_in[18];
    const float* out_W    = (const float*)d_in[19];
    const float* out_b    = (const float*)d_in[20];
    float* out = (float*)d_out;

    char* ws = (char*)d_ws;
    size_t o = 0;
    auto alloc = [&](size_t bytes)->char*{
        char* p = ws + o; o = (o + bytes + 255) & ~(size_t)255; return p;
    };
    bf16_t* ENC_OUT = (bf16_t*)alloc((size_t)LPRE*BATCH*HD*2);     // 30 MB
    bf16_t* HIST    = (bf16_t*)alloc((size_t)LFWD*BATCH*HD*2);     // 40 MB: emb_all (t<60) then h_hist
    bf16_t* FXB     = (bf16_t*)alloc((size_t)LFWD*BATCH*KIN*2);
    float*  HF0     = (float*) alloc((size_t)BATCH*HD*4);
    float*  HF1     = (float*) alloc((size_t)BATCH*HD*4);
    bf16_t* HB0     = (bf16_t*)alloc((size_t)BATCH*HD*2);
    bf16_t* HB1     = (bf16_t*)alloc((size_t)BATCH*HD*2);
    bf16_t* EBUF    = (bf16_t*)alloc((size_t)BATCH*HD*2);
    bf16_t* CTXB    = (bf16_t*)alloc((size_t)BATCH*HD*2);
    bf16_t* GBUF    = (bf16_t*)alloc((size_t)BATCH*HD*2);
    float*  AWB     = (float*) alloc((size_t)BATCH*80*4);
    float*  WFUSE   = (float*) alloc((size_t)256*256*4);
    float*  EBIAS   = (float*) alloc(256*4);
    float*  LB      = (float*) alloc(80*4);
    float*  LB0     = (float*) alloc(80*4);
    bf16_t* PACK_ENC = (bf16_t*)alloc(786432);
    bf16_t* PACK_DEC = (bf16_t*)alloc(786432);
    bf16_t* PACK_CMB = (bf16_t*)alloc(262144);
    bf16_t* PACK_E   = (bf16_t*)alloc(147456);
    bf16_t* PACK_BL  = (bf16_t*)alloc(46080);
    bf16_t* PACK_BL0 = (bf16_t*)alloc(46080);

    hipMemsetAsync(HF0, 0, (size_t)BATCH*HD*4, stream);
    hipMemsetAsync(HB0, 0, (size_t)BATCH*HD*2, stream);

    dim3 blk(256);
    // ---- prep (parallel, off critical path) ----
    emb_kernel<<<dim3(64,60), blk, 0, stream>>>(pre_x, pre_y, enc_embW, enc_embB, HIST);
    fxconv<<<dim3(1280), blk, 0, stream>>>(fwd_x, FXB);
    pack_gru<<<dim3(192), blk, 0, stream>>>(enc_Wih, enc_Whh, PACK_ENC);
    pack_gru<<<dim3(192), blk, 0, stream>>>(dec_Wih, dec_Whh, PACK_DEC);
    pack_B512<<<dim3(64), blk, 0, stream>>>(comb_W, PACK_CMB);
    wfuse_kernel<<<dim3(257), blk, 0, stream>>>(dec_embW, dec_embB, out_W, out_b, WFUSE, EBIAS);
    pack_e<<<dim3(36), blk, 0, stream>>>(WFUSE, dec_embW, PACK_E);
    pack_logits<<<dim3(24), blk, 0, stream>>>(WFUSE, dec_embW, attn_W, attn_b, dec_embB,
                                              EBIAS, PACK_BL, PACK_BL0, LB, LB0);

    float*  HF[2] = {HF0, HF1};
    bf16_t* HB[2] = {HB0, HB1};
    int p = 0;

    // ---- encoder ----
    for (int t = 0; t < LPRE; t++){
        gru_step<<<dim3(64,4), blk, 0, stream>>>(
            HIST + (size_t)t*BATCH*HD, HB[p], PACK_ENC, enc_bih, enc_bhh,
            HF[p], HF[p^1], HB[p^1], ENC_OUT + (size_t)t*BATCH*HD);
        p ^= 1;
    }
    // ---- decoder ----
    for (int t = 0; t < LFWD; t++){
        const bf16_t* fxt = FXB + (size_t)t*BATCH*KIN;
        e_kernel<<<dim3(64,4), blk, 0, stream>>>(
            HB[p], fxt, PACK_E, t ? EBIAS : dec_embB, t ? 0 : 8, EBUF);
        attn_kernel<<<dim3(64), blk, 0, stream>>>(
            HB[p], fxt, t ? PACK_BL : PACK_BL0, t ? LB : LB0, AWB);
        ctx_kernel<<<dim3(64,8), blk, 0, stream>>>(AWB, ENC_OUT, CTXB);
        comb_kernel<<<dim3(64,4), blk, 0, stream>>>(EBUF, CTXB, PACK_CMB, comb_b, GBUF);
        gru_step<<<dim3(64,4), blk, 0, stream>>>(
            GBUF, HB[p], PACK_DEC, dec_bih, dec_bhh,
            HF[p], HF[p^1], HB[p^1], HIST + (size_t)t*BATCH*HD);
        p ^= 1;
    }
    final_out<<<dim3(64,80), blk, 0, stream>>>(HIST, out_W, out_b, out);
}